// Round 16
// baseline (98.004 us; speedup 1.0000x reference)
//
#include <hip/hip_runtime.h>

// B=4, S=4096, D=64, fp32. Softmax over QUERY axis (per key-column norm):
//   out[b,q,:] = sum_k exp(s[q,k]) * (1/sum_q' exp(s[q',k])) * V[k,:],  s = Q.K^T/8
// v17 = v14 (proven best: apply 62.5us, total 96.1) + T5 s_setprio around every
// MFMA cluster (QK 6-chains, PV triplets, stats kg-clusters). Rationale: five
// structures all plateau 62-65us with MfmaUtil ~35%; lockstep phases contend for
// pipes with no arbitration -- the documented regime where setprio pays
// (+21-39% on phase-split GEMM). Zero register/numerics impact.

#define B_N 4
#define S_N 4096
#define D_N 64
#define BS_N (B_N * S_N)
#define NCHUNK 128            // 32-row chunks per batch
#define IMG_CH 8192           // bytes per chunk in every image
#define QSC (0.125f * 1.44269504088896f)

typedef __attribute__((ext_vector_type(4))) float f32x4;
typedef __attribute__((ext_vector_type(2))) float f32x2;
typedef __attribute__((ext_vector_type(8))) short short8;
typedef __attribute__((ext_vector_type(4))) unsigned u32x4;
typedef unsigned char uchar;

#define MFMA16(A, Bf, C) __builtin_amdgcn_mfma_f32_16x16x32_bf16((A), (Bf), (C), 0, 0, 0)

// Truncation hi/lo split: x == hi + lo + O(2^-16 x); residual exact in fp32.
__device__ __forceinline__ void split1(float x, unsigned short& h, unsigned short& l) {
  union { float f; unsigned u; } t; t.f = x;
  h = (unsigned short)(t.u >> 16);
  union { unsigned u; float f; } hv; hv.u = ((unsigned)h) << 16;
  union { float f; unsigned u; } r; r.f = x - hv.f;
  l = (unsigned short)(r.u >> 16);
}

__device__ __forceinline__ void splitFrag8(const f32x4 a, const f32x4 b, short8& hi, short8& lo) {
#pragma unroll
  for (int j = 0; j < 4; ++j) { unsigned short h, l; split1(a[j], h, l); hi[j] = (short)h; lo[j] = (short)l; }
#pragma unroll
  for (int j = 0; j < 4; ++j) { unsigned short h, l; split1(b[j], h, l); hi[4 + j] = (short)h; lo[4 + j] = (short)l; }
}

__device__ __forceinline__ void gld16(const void* g, void* l) {
  __builtin_amdgcn_global_load_lds((const __attribute__((address_space(1))) unsigned int*)g,
                                   (__attribute__((address_space(3))) unsigned int*)l, 16, 0, 0);
}

// ---------------------------------------------------------------------------
// prepKQ: fp32 [B*S][64] -> FRAGMENT-ORDERED chunk images (proven).
// ---------------------------------------------------------------------------
__global__ __launch_bounds__(256) void sdpa_prepKQ(const float* __restrict__ K,
                                                   const float* __restrict__ Qm,
                                                   uchar* __restrict__ Kimg,
                                                   uchar* __restrict__ Qimg) {
  const int sel = blockIdx.x >> 9;
  const int c = blockIdx.x & 127;
  const int b = (blockIdx.x >> 7) & 3;
  const float* src = sel ? Qm : K;
  uchar* img = sel ? Qimg : Kimg;
  const float scale = sel ? QSC : 1.0f;
  const int t = threadIdx.x;
  const int r = t >> 3;          // 0..31 row in chunk
  const int d0 = (t & 7) * 8;    // 0..56
  const float* s = src + ((size_t)(b * S_N + c * 32 + r)) * D_N + d0;
  f32x4 x0 = *(const f32x4*)(s);
  f32x4 x1 = *(const f32x4*)(s + 4);
  x0 *= scale; x1 *= scale;
  short8 h8, l8;
  splitFrag8(x0, x1, h8, l8);
  const int kt = r >> 4;
  const int lane = ((d0 & 31) >> 3) * 16 + (r & 15);
  const int ph = d0 >> 5;  // 0/1
  uchar* base = img + ((size_t)(b * NCHUNK + c)) * IMG_CH + kt * 4096 + lane * 16;
  *(short8*)(base + ph * 1024) = h8;
  *(short8*)(base + (2 + ph) * 1024) = l8;
}

// ---------------------------------------------------------------------------
// stats8: lPart[qs][b][k] = sum over q-slice qs (16 slices x 256 q) of exp2(s).
// grid 1024 (16 waves/CU), block 256; 64 k resident/wave; streams 8 Q chunks.
// + setprio around each kg MFMA cluster (T5).
// ---------------------------------------------------------------------------
__global__ __launch_bounds__(256, 4) void sdpa_stats8(const uchar* __restrict__ Kimg,
                                                      const uchar* __restrict__ Qimg,
                                                      float* __restrict__ lPart) {
  const int tid = threadIdx.x, lane = tid & 63, w = tid >> 6;
  const int l15 = lane & 15, g4 = lane >> 4;
  const int xcd = blockIdx.x & 7;
  const int b = xcd >> 1;
  const int r = blockIdx.x >> 3;                  // [0,128)
  const int kt = ((r & 31) << 1) | (xcd & 1);     // [0,64) 64-k tile
  const int qs = ((r >> 5) << 2) | w;             // [0,16) 256-q slice

  short8 kh[4][2], kl[4][2];
#pragma unroll
  for (int kg = 0; kg < 4; ++kg) {
    const uchar* kc = Kimg + ((size_t)(b * NCHUNK + kt * 2 + (kg >> 1))) * IMG_CH
                    + (kg & 1) * 4096 + lane * 16;
    kh[kg][0] = *(const short8*)(kc);
    kh[kg][1] = *(const short8*)(kc + 1024);
    kl[kg][0] = *(const short8*)(kc + 2048);
    kl[kg][1] = *(const short8*)(kc + 3072);
  }

  float lacc[4][4];
#pragma unroll
  for (int kg = 0; kg < 4; ++kg)
#pragma unroll
    for (int rr = 0; rr < 4; ++rr) lacc[kg][rr] = 0.f;

  const uchar* Qbase = Qimg + ((size_t)(b * NCHUNK + qs * 8)) * IMG_CH + lane * 16;

#pragma unroll 1
  for (int it = 0; it < 8; ++it) {
    const uchar* Qc = Qbase + (size_t)it * IMG_CH;
#pragma unroll
    for (int qt = 0; qt < 2; ++qt) {
      short8 bh0 = *(const short8*)(Qc + qt * 4096);
      short8 bh1 = *(const short8*)(Qc + qt * 4096 + 1024);
      short8 bl0 = *(const short8*)(Qc + qt * 4096 + 2048);
      short8 bl1 = *(const short8*)(Qc + qt * 4096 + 3072);
#pragma unroll
      for (int kg = 0; kg < 4; ++kg) {
        f32x4 acc = {0.f, 0.f, 0.f, 0.f};
        __builtin_amdgcn_s_setprio(1);
        acc = MFMA16(kl[kg][0], bh0, acc);
        acc = MFMA16(kh[kg][0], bl0, acc);
        acc = MFMA16(kh[kg][0], bh0, acc);
        acc = MFMA16(kl[kg][1], bh1, acc);
        acc = MFMA16(kh[kg][1], bl1, acc);
        acc = MFMA16(kh[kg][1], bh1, acc);
        __builtin_amdgcn_s_setprio(0);
#pragma unroll
        for (int rr = 0; rr < 4; ++rr)
          lacc[kg][rr] += exp2f(acc[rr]);
      }
    }
  }

#pragma unroll
  for (int off = 1; off < 16; off <<= 1)
#pragma unroll
    for (int kg = 0; kg < 4; ++kg)
#pragma unroll
      for (int rr = 0; rr < 4; ++rr)
        lacc[kg][rr] += __shfl_xor(lacc[kg][rr], off);

  if (l15 == 0) {
#pragma unroll
    for (int kg = 0; kg < 4; ++kg)
#pragma unroll
      for (int rr = 0; rr < 4; ++rr)
        lPart[(size_t)qs * BS_N + b * S_N + kt * 64 + kg * 16 + (g4 << 2) + rr] = lacc[kg][rr];
  }
}

// ---------------------------------------------------------------------------
// prepV7: fragment-ordered permuted VT image, rcpl computed inline (proven).
// ---------------------------------------------------------------------------
__global__ __launch_bounds__(256) void sdpa_prepV7(const float* __restrict__ V,
                                                   const float* __restrict__ lPart,
                                                   uchar* __restrict__ VT) {
  __shared__ float Vs[32][65];
  __shared__ float rls[32];
  const int c = blockIdx.x & 127;
  const int b = blockIdx.x >> 7;
  const int t = threadIdx.x;
  {
    const int k = t >> 3;
    const int d0 = (t & 7) * 8;
    const float* src = V + ((size_t)(b * S_N + c * 32 + k)) * D_N + d0;
    f32x4 x0 = *(const f32x4*)(src);
    f32x4 x1 = *(const f32x4*)(src + 4);
#pragma unroll
    for (int j = 0; j < 4; ++j) { Vs[k][d0 + j] = x0[j]; Vs[k][d0 + 4 + j] = x1[j]; }
    if (t < 32) {
      float s = 0.f;
      const float* lp = lPart + b * S_N + c * 32 + t;
#pragma unroll
      for (int j = 0; j < 16; ++j) s += lp[(size_t)j * BS_N];
      rls[t] = 1.0f / s;
    }
  }
  __syncthreads();
  const int d = t >> 2;
  const int kg = t & 3;
  short8 h8, l8;
#pragma unroll
  for (int j = 0; j < 8; ++j) {
    const int cc = kg * 8 + j;
    const int k = (((cc >> 2) & 1) << 4) + (((cc >> 3)) << 2) + (cc & 3);
    float v = Vs[k][d] * rls[k];
    unsigned short h, l; split1(v, h, l);
    h8[j] = (short)h; l8[j] = (short)l;
  }
  const int lane = kg * 16 + (d & 15);
  uchar* base = VT + ((size_t)(b * NCHUNK + c)) * IMG_CH + (d >> 4) * 2048 + lane * 16;
  *(short8*)(base) = h8;
  *(short8*)(base + 1024) = l8;
}

// ---------------------------------------------------------------------------
// apply17: v14 structure (grid 256 = b x qt(64 tiles of 64 q); block 1024 =
// 16 waves = qsub(2) x kq(8); V staged once by qsub0 into shared dbuf slab;
// K reg-loads duplicated, barrier-locked). Per iter (v13 rotation):
//   K(it) | SB | [prio1] PV(it-1) [prio0] | SB | qsub0 stage V(it) |
//   [prio1] QK-chains [prio0] + exp/pack | vmcnt(0) | barrier.
// ---------------------------------------------------------------------------
__global__ __launch_bounds__(1024, 4) void sdpa_apply17(const float* __restrict__ Q,
                                                        const uchar* __restrict__ Kimg,
                                                        const uchar* __restrict__ VTimg,
                                                        float* __restrict__ Out) {
  __shared__ __attribute__((aligned(16))) uchar sm[131072];  // V slabs; Comb aliases

  const int tid = threadIdx.x, lane = tid & 63, w = tid >> 6;
  const int l15 = lane & 15, g4 = lane >> 4;
  const int qsub = w >> 3, kq = w & 7;
  const int xcd = blockIdx.x & 7;
  const int b = xcd >> 1;
  const int qt = ((blockIdx.x >> 3) << 1) | (xcd & 1);  // [0,64), tiles of 64 q

  // Q B-frags: this wave's 32 q rows (2 x 16), scaled + hi/lo split
  short8 qh[2][2], ql[2][2];
#pragma unroll
  for (int qg = 0; qg < 2; ++qg) {
    const int qRow = qt * 64 + qsub * 32 + qg * 16 + l15;
    const float* Qp = Q + ((size_t)(b * S_N + qRow)) * D_N;
    f32x4 x0 = *(const f32x4*)(Qp + g4 * 8);
    f32x4 x1 = *(const f32x4*)(Qp + g4 * 8 + 4);
    f32x4 y0 = *(const f32x4*)(Qp + 32 + g4 * 8);
    f32x4 y1 = *(const f32x4*)(Qp + 36 + g4 * 8);
    x0 *= QSC; x1 *= QSC; y0 *= QSC; y1 *= QSC;
    splitFrag8(x0, x1, qh[qg][0], ql[qg][0]);
    splitFrag8(y0, y1, qh[qg][1], ql[qg][1]);
  }

  f32x4 accO[2][4];
#pragma unroll
  for (int qg = 0; qg < 2; ++qg)
#pragma unroll
    for (int dt = 0; dt < 4; ++dt) accO[qg][dt] = (f32x4){0.f, 0.f, 0.f, 0.f};

  const uchar* Kc = Kimg + ((size_t)(b * NCHUNK + kq * 16)) * IMG_CH + lane * 16;
  const uchar* Vc = VTimg + ((size_t)(b * NCHUNK + kq * 16)) * IMG_CH + lane * 16;
  uchar* const slab0 = sm + kq * 16384;   // [parity][8192]
  const int l16 = lane * 16;

  u32x4 paH[2], paL[2];                   // P regs: VALU-produced, loop-carried

#define QK_FROM(KB)                                                            \
  _Pragma("unroll")                                                            \
  for (int kt = 0; kt < 2; ++kt) {                                             \
    short8 ah0 = KB[kt][0], ah1 = KB[kt][1];                                   \
    short8 al0 = KB[kt][2], al1 = KB[kt][3];                                   \
    _Pragma("unroll")                                                          \
    for (int qg = 0; qg < 2; ++qg) {                                           \
      f32x4 acc = {0.f, 0.f, 0.f, 0.f};                                        \
      __builtin_amdgcn_s_setprio(1);                                           \
      acc = MFMA16(al0, qh[qg][0], acc);                                       \
      acc = MFMA16(ah0, ql[qg][0], acc);                                       \
      acc = MFMA16(ah0, qh[qg][0], acc);                                       \
      acc = MFMA16(al1, qh[qg][1], acc);                                       \
      acc = MFMA16(ah1, ql[qg][1], acc);                                       \
      acc = MFMA16(ah1, qh[qg][1], acc);                                       \
      __builtin_amdgcn_s_setprio(0);                                           \
      _Pragma("unroll")                                                        \
      for (int pair = 0; pair < 2; ++pair) {                                   \
        float p0 = exp2f(acc[2 * pair + 0]);                                   \
        float p1 = exp2f(acc[2 * pair + 1]);                                   \
        unsigned short h0, l0, h1, l1;                                         \
        split1(p0, h0, l0);                                                    \
        split1(p1, h1, l1);                                                    \
        paH[qg][kt * 2 + pair] = (unsigned)h0 | ((unsigned)h1 << 16);          \
        paL[qg][kt * 2 + pair] = (unsigned)l0 | ((unsigned)l1 << 16);          \
      }                                                                        \
    }                                                                          \
  }

#define PV_STEP(SLAB)                                                          \
  {                                                                            \
    short8 pah[2], pal[2];                                                     \
    _Pragma("unroll")                                                          \
    for (int qg = 0; qg < 2; ++qg) {                                           \
      pah[qg] = __builtin_bit_cast(short8, paH[qg]);                           \
      pal[qg] = __builtin_bit_cast(short8, paL[qg]);                           \
    }                                                                          \
    __builtin_amdgcn_s_setprio(1);                                             \
    _Pragma("unroll")                                                          \
    for (int dt = 0; dt < 4; ++dt) {                                           \
      short8 vh = *(const short8*)((SLAB) + dt * 2048 + l16);                  \
      short8 vl = *(const short8*)((SLAB) + dt * 2048 + 1024 + l16);           \
      _Pragma("unroll")                                                        \
      for (int qg = 0; qg < 2; ++qg) {                                         \
        accO[qg][dt] = MFMA16(pal[qg], vh, accO[qg][dt]);                      \
        accO[qg][dt] = MFMA16(pah[qg], vl, accO[qg][dt]);                      \
        accO[qg][dt] = MFMA16(pah[qg], vh, accO[qg][dt]);                      \
      }                                                                        \
    }                                                                          \
    __builtin_amdgcn_s_setprio(0);                                             \
  }

  // prologue: K(0), V(0)->slab[0] (qsub0 only), QK(0), pin, barrier
  {
    short8 kb[2][4];
#pragma unroll
    for (int kt = 0; kt < 2; ++kt)
#pragma unroll
      for (int p = 0; p < 4; ++p)
        kb[kt][p] = *(const short8*)(Kc + (kt * 4 + p) * 1024);
    if (qsub == 0) {
#pragma unroll
      for (int s = 0; s < 8; ++s)
        gld16(Vc + s * 1024, slab0 + s * 1024);
    }
    QK_FROM(kb)
    asm volatile("s_waitcnt vmcnt(0)" ::: "memory");
    __syncthreads();
  }

#pragma unroll 1
  for (int it = 1; it < 16; ++it) {
    // K(it): transient regs, issued FIRST (covered by PV below)
    short8 kb[2][4];
    {
      const uchar* Kn = Kc + (size_t)it * IMG_CH;
#pragma unroll
      for (int kt = 0; kt < 2; ++kt)
#pragma unroll
        for (int p = 0; p < 4; ++p)
          kb[kt][p] = *(const short8*)(Kn + (kt * 4 + p) * 1024);
    }
    __builtin_amdgcn_sched_barrier(0);  // K loads issue before PV

    PV_STEP(slab0 + ((it - 1) & 1) * 8192)  // PV(it-1) covers K(it) latency

    __builtin_amdgcn_sched_barrier(0);  // slab reads before staging

    // V(it) -> shared slab parity it&1 (qsub0 only; covered by QK+exp)
    if (qsub == 0) {
      const uchar* Vn = Vc + (size_t)it * IMG_CH;
      uchar* slabW = slab0 + (it & 1) * 8192;
#pragma unroll
      for (int s = 0; s < 8; ++s)
        gld16(Vn + s * 1024, slabW + s * 1024);
    }

    QK_FROM(kb)  // K landed during PV

    asm volatile("s_waitcnt vmcnt(0)" ::: "memory");  // V(it) staged
    __syncthreads();  // V(it) visible to both qsub waves; streams stay locked
  }

  PV_STEP(slab0 + 8192)  // epilogue: PV(15), parity 1

#undef QK_FROM
#undef PV_STEP

  // merge 8 kq partials per qsub, two 16-q phases (Comb aliases the V slabs)
  float* Comb = (float*)sm;
#pragma unroll
  for (int qg = 0; qg < 2; ++qg) {
    __syncthreads();   // all waves' slab reads done / previous phase consumed
    {
      float* CombW = Comb + w * (16 * 68);
#pragma unroll
      for (int dt = 0; dt < 4; ++dt)
#pragma unroll
        for (int r = 0; r < 4; ++r)
          CombW[((g4 << 2) + r) * 68 + dt * 16 + l15] = accO[qg][dt][r];
    }
    __syncthreads();
    {
      const int qs2 = tid >> 9;            // 0..1
      const int row = (tid >> 5) & 15;     // 0..15
      const int c2 = (tid & 31) * 2;       // 0..62
      f32x2 s = {0.f, 0.f};
#pragma unroll
      for (int kq2 = 0; kq2 < 8; ++kq2)
        s += *(const f32x2*)(Comb + (qs2 * 8 + kq2) * (16 * 68) + row * 68 + c2);
      *(f32x2*)(Out + ((size_t)(b * S_N + qt * 64 + qs2 * 32 + qg * 16 + row)) * D_N + c2) = s;
    }
  }
}

extern "C" void kernel_launch(void* const* d_in, const int* in_sizes, int n_in,
                              void* d_out, int out_size, void* d_ws, size_t ws_size,
                              hipStream_t stream) {
  (void)in_sizes; (void)n_in; (void)out_size;
  const float* Q = (const float*)d_in[0];
  const float* K = (const float*)d_in[1];
  const float* V = (const float*)d_in[2];
  float* out = (float*)d_out;
  uchar* ws = (uchar*)d_ws;

  const size_t imgSz = (size_t)B_N * NCHUNK * IMG_CH;          // 4 MB
  const size_t offK = 0;
  const size_t offQV = imgSz;                                  // Q image; VT aliases after stats
  const size_t offLP = 2 * imgSz;
  const size_t need = offLP + (size_t)16 * BS_N * 4;           // ~9.05 MB (proven available)

  if (ws_size < need) return;
  float* lPart = (float*)(ws + offLP);

  sdpa_prepKQ<<<dim3(1024), dim3(256), 0, stream>>>(K, Q, ws + offK, ws + offQV);
  sdpa_stats8<<<dim3(1024), dim3(256), 0, stream>>>(ws + offK, ws + offQV, lPart);
  sdpa_prepV7<<<dim3(512), dim3(256), 0, stream>>>(V, lPart, ws + offQV);
  sdpa_apply17<<<dim3(256), dim3(1024), 0, stream>>>(Q, ws + offK, ws + offQV, out);
}

// Round 17
// 75.188 us; speedup vs baseline: 1.3034x; 1.3034x over previous
//
#include <hip/hip_runtime.h>

// B=4, S=4096, D=64, fp32. Softmax over QUERY axis (per key-column norm):
//   out[b,q,:] = sum_k exp(s[q,k]) * (1/sum_q' exp(s[q',k])) * V[k,:],  s = Q.K^T/8
// v18 = v14 (proven best; setprio reverted - null) + targeted precision cuts:
//   - stats in SINGLE fp16 (2 MFMA/64-dot vs 6): L averages 4096 independent
//     errors -> ~1e-5 rel. Safe.
//   - PV in SINGLE fp16 (1 MFMA/32-dot vs 3): adds ~1e-4 abs to out. V image
//     4KB/chunk; P-pack = plain f16 casts. Permuted-VT mapping unchanged.
//   - apply QK stays bf16 hi/lo (scores are the sensitive path).
// ws: Khl 4MB | K16 2MB | Q16/VT16 2MB (aliased) | lPart 1MB = 9.05MB (proven).

#define B_N 4
#define S_N 4096
#define D_N 64
#define BS_N (B_N * S_N)
#define NCHUNK 128            // 32-row chunks per batch
#define IMG_CH 8192           // bytes per chunk, bf16 hi/lo image
#define IMG_CH16 4096         // bytes per chunk, fp16 images
#define QSC (0.125f * 1.44269504088896f)

typedef __attribute__((ext_vector_type(4))) float f32x4;
typedef __attribute__((ext_vector_type(2))) float f32x2;
typedef __attribute__((ext_vector_type(8))) short short8;
typedef __attribute__((ext_vector_type(8))) _Float16 half8;
typedef unsigned char uchar;

#define MFMA16(A, Bf, C) __builtin_amdgcn_mfma_f32_16x16x32_bf16((A), (Bf), (C), 0, 0, 0)
#define MFMAH(A, Bf, C) __builtin_amdgcn_mfma_f32_16x16x32_f16((A), (Bf), (C), 0, 0, 0)

// Truncation hi/lo split: x == hi + lo + O(2^-16 x); residual exact in fp32.
__device__ __forceinline__ void split1(float x, unsigned short& h, unsigned short& l) {
  union { float f; unsigned u; } t; t.f = x;
  h = (unsigned short)(t.u >> 16);
  union { unsigned u; float f; } hv; hv.u = ((unsigned)h) << 16;
  union { float f; unsigned u; } r; r.f = x - hv.f;
  l = (unsigned short)(r.u >> 16);
}

__device__ __forceinline__ void splitFrag8(const f32x4 a, const f32x4 b, short8& hi, short8& lo) {
#pragma unroll
  for (int j = 0; j < 4; ++j) { unsigned short h, l; split1(a[j], h, l); hi[j] = (short)h; lo[j] = (short)l; }
#pragma unroll
  for (int j = 0; j < 4; ++j) { unsigned short h, l; split1(b[j], h, l); hi[4 + j] = (short)h; lo[4 + j] = (short)l; }
}

__device__ __forceinline__ void gld16(const void* g, void* l) {
  __builtin_amdgcn_global_load_lds((const __attribute__((address_space(1))) unsigned int*)g,
                                   (__attribute__((address_space(3))) unsigned int*)l, 16, 0, 0);
}

// ---------------------------------------------------------------------------
// prepKQ: K blocks write Khl (bf16 hi/lo, 8KB/chunk) AND K16 (fp16, 4KB/chunk);
// Q blocks write Q16 (fp16, scaled by QSC). Fragment-ordered.
// fp16 chunk: kt(2) x dh(2) x 1KB; lane = ((d0&31)>>3)*16 + (r&15).
// ---------------------------------------------------------------------------
__global__ __launch_bounds__(256) void sdpa_prepKQ(const float* __restrict__ K,
                                                   const float* __restrict__ Qm,
                                                   uchar* __restrict__ Khl,
                                                   uchar* __restrict__ K16,
                                                   uchar* __restrict__ Q16) {
  const int sel = blockIdx.x >> 9;
  const int c = blockIdx.x & 127;
  const int b = (blockIdx.x >> 7) & 3;
  const int t = threadIdx.x;
  const int r = t >> 3;          // 0..31 row in chunk
  const int d0 = (t & 7) * 8;    // 0..56
  const float* src = (sel ? Qm : K) + ((size_t)(b * S_N + c * 32 + r)) * D_N + d0;
  f32x4 x0 = *(const f32x4*)(src);
  f32x4 x1 = *(const f32x4*)(src + 4);
  const int kt = r >> 4;
  const int lane = ((d0 & 31) >> 3) * 16 + (r & 15);
  const size_t ch16 = ((size_t)(b * NCHUNK + c)) * IMG_CH16 + kt * 2048 + (d0 >> 5) * 1024 + lane * 16;

  if (sel == 0) {
    // Khl (unscaled)
    short8 h8, l8;
    splitFrag8(x0, x1, h8, l8);
    const int ph = d0 >> 5;
    uchar* base = Khl + ((size_t)(b * NCHUNK + c)) * IMG_CH + kt * 4096 + lane * 16;
    *(short8*)(base + ph * 1024) = h8;
    *(short8*)(base + (2 + ph) * 1024) = l8;
    // K16 (unscaled fp16)
    half8 hf;
#pragma unroll
    for (int j = 0; j < 4; ++j) { hf[j] = (_Float16)x0[j]; hf[4 + j] = (_Float16)x1[j]; }
    *(half8*)(K16 + ch16) = hf;
  } else {
    x0 *= QSC; x1 *= QSC;
    half8 hf;
#pragma unroll
    for (int j = 0; j < 4; ++j) { hf[j] = (_Float16)x0[j]; hf[4 + j] = (_Float16)x1[j]; }
    *(half8*)(Q16 + ch16) = hf;
  }
}

// ---------------------------------------------------------------------------
// stats16: lPart[qs][b][k] = sum over q-slice qs (16 x 256 q) of exp2(s).
// SINGLE fp16 (2 MFMAs per 64-dot). grid 1024, block 256; 64 k resident/wave.
// ---------------------------------------------------------------------------
__global__ __launch_bounds__(256, 4) void sdpa_stats16(const uchar* __restrict__ K16,
                                                       const uchar* __restrict__ Q16,
                                                       float* __restrict__ lPart) {
  const int tid = threadIdx.x, lane = tid & 63, w = tid >> 6;
  const int l15 = lane & 15, g4 = lane >> 4;
  const int xcd = blockIdx.x & 7;
  const int b = xcd >> 1;
  const int r = blockIdx.x >> 3;                  // [0,128)
  const int kt = ((r & 31) << 1) | (xcd & 1);     // [0,64) 64-k tile
  const int qs = ((r >> 5) << 2) | w;             // [0,16) 256-q slice

  // K resident: kg 0..3 -> chunk kt*2+(kg>>1), 16-row half kg&1; dh 0..1
  half8 kf[4][2];
#pragma unroll
  for (int kg = 0; kg < 4; ++kg) {
    const uchar* kc = K16 + ((size_t)(b * NCHUNK + kt * 2 + (kg >> 1))) * IMG_CH16
                    + (kg & 1) * 2048 + lane * 16;
    kf[kg][0] = *(const half8*)(kc);
    kf[kg][1] = *(const half8*)(kc + 1024);
  }

  float lacc[4][4];
#pragma unroll
  for (int kg = 0; kg < 4; ++kg)
#pragma unroll
    for (int rr = 0; rr < 4; ++rr) lacc[kg][rr] = 0.f;

  const uchar* Qbase = Q16 + ((size_t)(b * NCHUNK + qs * 8)) * IMG_CH16 + lane * 16;

#pragma unroll 1
  for (int it = 0; it < 8; ++it) {
    const uchar* Qc = Qbase + (size_t)it * IMG_CH16;
#pragma unroll
    for (int qt = 0; qt < 2; ++qt) {
      half8 qf0 = *(const half8*)(Qc + qt * 2048);
      half8 qf1 = *(const half8*)(Qc + qt * 2048 + 1024);
#pragma unroll
      for (int kg = 0; kg < 4; ++kg) {
        f32x4 acc = {0.f, 0.f, 0.f, 0.f};
        acc = MFMAH(kf[kg][0], qf0, acc);
        acc = MFMAH(kf[kg][1], qf1, acc);
#pragma unroll
        for (int rr = 0; rr < 4; ++rr)
          lacc[kg][rr] += exp2f(acc[rr]);
      }
    }
  }

#pragma unroll
  for (int off = 1; off < 16; off <<= 1)
#pragma unroll
    for (int kg = 0; kg < 4; ++kg)
#pragma unroll
      for (int rr = 0; rr < 4; ++rr)
        lacc[kg][rr] += __shfl_xor(lacc[kg][rr], off);

  if (l15 == 0) {
#pragma unroll
    for (int kg = 0; kg < 4; ++kg)
#pragma unroll
      for (int rr = 0; rr < 4; ++rr)
        lPart[(size_t)qs * BS_N + b * S_N + kt * 64 + kg * 16 + (g4 << 2) + rr] = lacc[kg][rr];
  }
}

// ---------------------------------------------------------------------------
// prepV8: fp16 permuted VT image (4KB/chunk), rcpl folded (finalize fused).
// Chunk = 4 dt x 1KB; lane = kslotgrp*16 + (d&15); 8 fp16 k-slots per lane.
// ---------------------------------------------------------------------------
__global__ __launch_bounds__(256) void sdpa_prepV8(const float* __restrict__ V,
                                                   const float* __restrict__ lPart,
                                                   uchar* __restrict__ VT) {
  __shared__ float Vs[32][65];
  __shared__ float rls[32];
  const int c = blockIdx.x & 127;
  const int b = blockIdx.x >> 7;
  const int t = threadIdx.x;
  {
    const int k = t >> 3;
    const int d0 = (t & 7) * 8;
    const float* src = V + ((size_t)(b * S_N + c * 32 + k)) * D_N + d0;
    f32x4 x0 = *(const f32x4*)(src);
    f32x4 x1 = *(const f32x4*)(src + 4);
#pragma unroll
    for (int j = 0; j < 4; ++j) { Vs[k][d0 + j] = x0[j]; Vs[k][d0 + 4 + j] = x1[j]; }
    if (t < 32) {
      float s = 0.f;
      const float* lp = lPart + b * S_N + c * 32 + t;
#pragma unroll
      for (int j = 0; j < 16; ++j) s += lp[(size_t)j * BS_N];
      rls[t] = 1.0f / s;
    }
  }
  __syncthreads();
  const int d = t >> 2;
  const int kg = t & 3;
  half8 hf;
#pragma unroll
  for (int j = 0; j < 8; ++j) {
    const int cc = kg * 8 + j;
    const int k = (((cc >> 2) & 1) << 4) + (((cc >> 3)) << 2) + (cc & 3);
    hf[j] = (_Float16)(Vs[k][d] * rls[k]);
  }
  const int lane = kg * 16 + (d & 15);
  *(half8*)(VT + ((size_t)(b * NCHUNK + c)) * IMG_CH16 + (d >> 4) * 1024 + lane * 16) = hf;
}

// ---------------------------------------------------------------------------
// apply18: v14 structure. grid 256 = b x qt(64 tiles of 64 q); block 1024 =
// 16 waves = qsub(2) x kq(8). V (fp16, 4KB/chunk) staged once by qsub0 into
// shared dbuf slab; K (bf16 hi/lo) reg-loads duplicated, barrier-locked.
// Per iter (v13 rotation): K(it) | SB | PV(it-1) fp16 (8 MFMA) | SB |
// qsub0 stage V(it) | QK(it) bf16 hi/lo (24 MFMA) + f16 pack | vmcnt(0) | bar.
// LDS: 8 kq x 2 x 4KB = 64KB; merge Comb (69.6KB) aliases -> sm 69632.
// ---------------------------------------------------------------------------
__global__ __launch_bounds__(1024, 4) void sdpa_apply18(const float* __restrict__ Q,
                                                        const uchar* __restrict__ Kimg,
                                                        const uchar* __restrict__ VTimg,
                                                        float* __restrict__ Out) {
  __shared__ __attribute__((aligned(16))) uchar sm[69632];  // V slabs (64KB); Comb aliases

  const int tid = threadIdx.x, lane = tid & 63, w = tid >> 6;
  const int l15 = lane & 15, g4 = lane >> 4;
  const int qsub = w >> 3, kq = w & 7;
  const int xcd = blockIdx.x & 7;
  const int b = xcd >> 1;
  const int qt = ((blockIdx.x >> 3) << 1) | (xcd & 1);  // [0,64), tiles of 64 q

  // Q B-frags: this wave's 32 q rows (2 x 16), scaled + hi/lo split
  short8 qh[2][2], ql[2][2];
#pragma unroll
  for (int qg = 0; qg < 2; ++qg) {
    const int qRow = qt * 64 + qsub * 32 + qg * 16 + l15;
    const float* Qp = Q + ((size_t)(b * S_N + qRow)) * D_N;
    f32x4 x0 = *(const f32x4*)(Qp + g4 * 8);
    f32x4 x1 = *(const f32x4*)(Qp + g4 * 8 + 4);
    f32x4 y0 = *(const f32x4*)(Qp + 32 + g4 * 8);
    f32x4 y1 = *(const f32x4*)(Qp + 36 + g4 * 8);
    x0 *= QSC; x1 *= QSC; y0 *= QSC; y1 *= QSC;
    splitFrag8(x0, x1, qh[qg][0], ql[qg][0]);
    splitFrag8(y0, y1, qh[qg][1], ql[qg][1]);
  }

  f32x4 accO[2][4];
#pragma unroll
  for (int qg = 0; qg < 2; ++qg)
#pragma unroll
    for (int dt = 0; dt < 4; ++dt) accO[qg][dt] = (f32x4){0.f, 0.f, 0.f, 0.f};

  const uchar* Kc = Kimg + ((size_t)(b * NCHUNK + kq * 16)) * IMG_CH + lane * 16;
  const uchar* Vc = VTimg + ((size_t)(b * NCHUNK + kq * 16)) * IMG_CH16 + lane * 16;
  uchar* const slab0 = sm + kq * 8192;    // [parity][4096]
  const int l16 = lane * 16;

  half8 paF[2];                           // P fp16 frags: VALU-produced, loop-carried

#define QK_FROM(KB)                                                            \
  _Pragma("unroll")                                                            \
  for (int kt = 0; kt < 2; ++kt) {                                             \
    short8 ah0 = KB[kt][0], ah1 = KB[kt][1];                                   \
    short8 al0 = KB[kt][2], al1 = KB[kt][3];                                   \
    _Pragma("unroll")                                                          \
    for (int qg = 0; qg < 2; ++qg) {                                           \
      f32x4 acc = {0.f, 0.f, 0.f, 0.f};                                        \
      acc = MFMA16(al0, qh[qg][0], acc);                                       \
      acc = MFMA16(ah0, ql[qg][0], acc);                                       \
      acc = MFMA16(ah0, qh[qg][0], acc);                                       \
      acc = MFMA16(al1, qh[qg][1], acc);                                       \
      acc = MFMA16(ah1, ql[qg][1], acc);                                       \
      acc = MFMA16(ah1, qh[qg][1], acc);                                       \
      _Pragma("unroll")                                                        \
      for (int rr = 0; rr < 4; ++rr)                                           \
        paF[qg][kt * 4 + rr] = (_Float16)exp2f(acc[rr]);                       \
    }                                                                          \
  }

#define PV_STEP(SLAB)                                                          \
  {                                                                            \
    _Pragma("unroll")                                                          \
    for (int dt = 0; dt < 4; ++dt) {                                           \
      half8 vf = *(const half8*)((SLAB) + dt * 1024 + l16);                    \
      _Pragma("unroll")                                                        \
      for (int qg = 0; qg < 2; ++qg)                                           \
        accO[qg][dt] = MFMAH(paF[qg], vf, accO[qg][dt]);                       \
    }                                                                          \
  }

  // prologue: K(0), V(0)->slab[0] (qsub0 only), QK(0), pin, barrier
  {
    short8 kb[2][4];
#pragma unroll
    for (int kt = 0; kt < 2; ++kt)
#pragma unroll
      for (int p = 0; p < 4; ++p)
        kb[kt][p] = *(const short8*)(Kc + (kt * 4 + p) * 1024);
    if (qsub == 0) {
#pragma unroll
      for (int s = 0; s < 4; ++s)
        gld16(Vc + s * 1024, slab0 + s * 1024);
    }
    QK_FROM(kb)
    asm volatile("s_waitcnt vmcnt(0)" ::: "memory");
    __syncthreads();
  }

#pragma unroll 1
  for (int it = 1; it < 16; ++it) {
    // K(it): transient regs, issued FIRST (covered by PV below)
    short8 kb[2][4];
    {
      const uchar* Kn = Kc + (size_t)it * IMG_CH;
#pragma unroll
      for (int kt = 0; kt < 2; ++kt)
#pragma unroll
        for (int p = 0; p < 4; ++p)
          kb[kt][p] = *(const short8*)(Kn + (kt * 4 + p) * 1024);
    }
    __builtin_amdgcn_sched_barrier(0);  // K loads issue before PV

    PV_STEP(slab0 + ((it - 1) & 1) * 4096)  // PV(it-1) covers K(it) latency

    __builtin_amdgcn_sched_barrier(0);  // slab reads before staging

    // V(it) -> shared slab parity it&1 (qsub0 only; covered by QK+exp)
    if (qsub == 0) {
      const uchar* Vn = Vc + (size_t)it * IMG_CH16;
      uchar* slabW = slab0 + (it & 1) * 4096;
#pragma unroll
      for (int s = 0; s < 4; ++s)
        gld16(Vn + s * 1024, slabW + s * 1024);
    }

    QK_FROM(kb)  // K landed during PV

    asm volatile("s_waitcnt vmcnt(0)" ::: "memory");  // V(it) staged
    __syncthreads();  // V(it) visible to both qsub waves; streams stay locked
  }

  PV_STEP(slab0 + 4096)  // epilogue: PV(15), parity 1

#undef QK_FROM
#undef PV_STEP

  // merge 8 kq partials per qsub, two 16-q phases (Comb aliases the V slabs)
  float* Comb = (float*)sm;
#pragma unroll
  for (int qg = 0; qg < 2; ++qg) {
    __syncthreads();   // all waves' slab reads done / previous phase consumed
    {
      float* CombW = Comb + w * (16 * 68);
#pragma unroll
      for (int dt = 0; dt < 4; ++dt)
#pragma unroll
        for (int r = 0; r < 4; ++r)
          CombW[((g4 << 2) + r) * 68 + dt * 16 + l15] = accO[qg][dt][r];
    }
    __syncthreads();
    {
      const int qs2 = tid >> 9;            // 0..1
      const int row = (tid >> 5) & 15;     // 0..15
      const int c2 = (tid & 31) * 2;       // 0..62
      f32x2 s = {0.f, 0.f};
#pragma unroll
      for (int kq2 = 0; kq2 < 8; ++kq2)
        s += *(const f32x2*)(Comb + (qs2 * 8 + kq2) * (16 * 68) + row * 68 + c2);
      *(f32x2*)(Out + ((size_t)(b * S_N + qt * 64 + qs2 * 32 + qg * 16 + row)) * D_N + c2) = s;
    }
  }
}

extern "C" void kernel_launch(void* const* d_in, const int* in_sizes, int n_in,
                              void* d_out, int out_size, void* d_ws, size_t ws_size,
                              hipStream_t stream) {
  (void)in_sizes; (void)n_in; (void)out_size;
  const float* Q = (const float*)d_in[0];
  const float* K = (const float*)d_in[1];
  const float* V = (const float*)d_in[2];
  float* out = (float*)d_out;
  uchar* ws = (uchar*)d_ws;

  const size_t offKhl = 0;                                     // 4 MB
  const size_t offK16 = (size_t)B_N * NCHUNK * IMG_CH;         // +2 MB
  const size_t offQ16 = offK16 + (size_t)B_N * NCHUNK * IMG_CH16;  // +2 MB (VT16 aliases)
  const size_t offLP = offQ16 + (size_t)B_N * NCHUNK * IMG_CH16;   // +1 MB
  const size_t need = offLP + (size_t)16 * BS_N * 4;           // 9.05 MB (proven)

  if (ws_size < need) return;
  float* lPart = (float*)(ws + offLP);

  sdpa_prepKQ<<<dim3(1024), dim3(256), 0, stream>>>(K, Q, ws + offKhl, ws + offK16, ws + offQ16);
  sdpa_stats16<<<dim3(1024), dim3(256), 0, stream>>>(ws + offK16, ws + offQ16, lPart);
  sdpa_prepV8<<<dim3(512), dim3(256), 0, stream>>>(V, lPart, ws + offQ16);
  sdpa_apply18<<<dim3(256), dim3(1024), 0, stream>>>(Q, ws + offKhl, ws + offQ16, out);
}

// Round 18
// 61.463 us; speedup vs baseline: 1.5945x; 1.2233x over previous
//
#include <hip/hip_runtime.h>

// B=4, S=4096, D=64, fp32. Softmax over QUERY axis (per key-column norm):
//   out[b,q,:] = sum_k exp(s[q,k]) * (1/sum_q' exp(s[q',k])) * V[k,:],  s = Q.K^T/8
// v19: FULL-fp16 apply + K STAGED LIKE V. Bytes model closed (v14 192KB/iter=
// 9375cy, v18 160KB=7470cy @ ~20B/cy/CU): apply is load-bytes-bound, K (bf16
// hi/lo, duplicated per qsub pair) is 80% of bytes. Now: QK uses the SAME fp16
// scores stats already uses (K16 4KB/chunk), and K is staged once per kq-group
// into LDS (qsub1 stages K(it+1), qsub0 stages V(it+1)) -> 64KB/iter (~3300cy
// floor). QK 24->8 MFMA; no hi/lo splits anywhere; P iteration-local (no
// loop-carried load-class state). Khl image deleted (ws 5.05MB).

#define B_N 4
#define S_N 4096
#define D_N 64
#define BS_N (B_N * S_N)
#define NCHUNK 128            // 32-row chunks per batch
#define IMG_CH16 4096         // bytes per chunk, fp16 images
#define QSC (0.125f * 1.44269504088896f)

typedef __attribute__((ext_vector_type(4))) float f32x4;
typedef __attribute__((ext_vector_type(2))) float f32x2;
typedef __attribute__((ext_vector_type(8))) _Float16 half8;
typedef unsigned char uchar;

#define MFMAH(A, Bf, C) __builtin_amdgcn_mfma_f32_16x16x32_f16((A), (Bf), (C), 0, 0, 0)

__device__ __forceinline__ void gld16(const void* g, void* l) {
  __builtin_amdgcn_global_load_lds((const __attribute__((address_space(1))) unsigned int*)g,
                                   (__attribute__((address_space(3))) unsigned int*)l, 16, 0, 0);
}

// ---------------------------------------------------------------------------
// prepKQ19: fp32 [B*S][64] -> fp16 fragment-ordered chunk images.
// Chunk (4KB) = kt(2) x dh(2) x 1KB; lane = ((d0&31)>>3)*16 + (r&15).
// grid 1024: blocks 0..511 = K (scale 1), 512..1023 = Q (scale QSC).
// ---------------------------------------------------------------------------
__global__ __launch_bounds__(256) void sdpa_prepKQ19(const float* __restrict__ K,
                                                     const float* __restrict__ Qm,
                                                     uchar* __restrict__ K16,
                                                     uchar* __restrict__ Q16) {
  const int sel = blockIdx.x >> 9;
  const int c = blockIdx.x & 127;
  const int b = (blockIdx.x >> 7) & 3;
  const int t = threadIdx.x;
  const int r = t >> 3;          // 0..31 row in chunk
  const int d0 = (t & 7) * 8;    // 0..56
  const float* src = (sel ? Qm : K) + ((size_t)(b * S_N + c * 32 + r)) * D_N + d0;
  f32x4 x0 = *(const f32x4*)(src);
  f32x4 x1 = *(const f32x4*)(src + 4);
  const float scale = sel ? QSC : 1.0f;
  x0 *= scale; x1 *= scale;
  half8 hf;
#pragma unroll
  for (int j = 0; j < 4; ++j) { hf[j] = (_Float16)x0[j]; hf[4 + j] = (_Float16)x1[j]; }
  const int kt = r >> 4;
  const int lane = ((d0 & 31) >> 3) * 16 + (r & 15);
  uchar* img = sel ? Q16 : K16;
  *(half8*)(img + ((size_t)(b * NCHUNK + c)) * IMG_CH16 + kt * 2048 + (d0 >> 5) * 1024 + lane * 16) = hf;
}

// ---------------------------------------------------------------------------
// stats16: lPart[qs][b][k] = sum over q-slice qs (16 x 256 q) of exp2(s).
// fp16 (2 MFMAs per 64-dot). grid 1024, block 256; 64 k resident/wave. (proven)
// ---------------------------------------------------------------------------
__global__ __launch_bounds__(256, 4) void sdpa_stats16(const uchar* __restrict__ K16,
                                                       const uchar* __restrict__ Q16,
                                                       float* __restrict__ lPart) {
  const int tid = threadIdx.x, lane = tid & 63, w = tid >> 6;
  const int l15 = lane & 15, g4 = lane >> 4;
  const int xcd = blockIdx.x & 7;
  const int b = xcd >> 1;
  const int r = blockIdx.x >> 3;                  // [0,128)
  const int kt = ((r & 31) << 1) | (xcd & 1);     // [0,64) 64-k tile
  const int qs = ((r >> 5) << 2) | w;             // [0,16) 256-q slice

  half8 kf[4][2];
#pragma unroll
  for (int kg = 0; kg < 4; ++kg) {
    const uchar* kc = K16 + ((size_t)(b * NCHUNK + kt * 2 + (kg >> 1))) * IMG_CH16
                    + (kg & 1) * 2048 + lane * 16;
    kf[kg][0] = *(const half8*)(kc);
    kf[kg][1] = *(const half8*)(kc + 1024);
  }

  float lacc[4][4];
#pragma unroll
  for (int kg = 0; kg < 4; ++kg)
#pragma unroll
    for (int rr = 0; rr < 4; ++rr) lacc[kg][rr] = 0.f;

  const uchar* Qbase = Q16 + ((size_t)(b * NCHUNK + qs * 8)) * IMG_CH16 + lane * 16;

#pragma unroll 1
  for (int it = 0; it < 8; ++it) {
    const uchar* Qc = Qbase + (size_t)it * IMG_CH16;
#pragma unroll
    for (int qt = 0; qt < 2; ++qt) {
      half8 qf0 = *(const half8*)(Qc + qt * 2048);
      half8 qf1 = *(const half8*)(Qc + qt * 2048 + 1024);
#pragma unroll
      for (int kg = 0; kg < 4; ++kg) {
        f32x4 acc = {0.f, 0.f, 0.f, 0.f};
        acc = MFMAH(kf[kg][0], qf0, acc);
        acc = MFMAH(kf[kg][1], qf1, acc);
#pragma unroll
        for (int rr = 0; rr < 4; ++rr)
          lacc[kg][rr] += exp2f(acc[rr]);
      }
    }
  }

#pragma unroll
  for (int off = 1; off < 16; off <<= 1)
#pragma unroll
    for (int kg = 0; kg < 4; ++kg)
#pragma unroll
      for (int rr = 0; rr < 4; ++rr)
        lacc[kg][rr] += __shfl_xor(lacc[kg][rr], off);

  if (l15 == 0) {
#pragma unroll
    for (int kg = 0; kg < 4; ++kg)
#pragma unroll
      for (int rr = 0; rr < 4; ++rr)
        lPart[(size_t)qs * BS_N + b * S_N + kt * 64 + kg * 16 + (g4 << 2) + rr] = lacc[kg][rr];
  }
}

// ---------------------------------------------------------------------------
// prepV8: fp16 permuted VT image (4KB/chunk), rcpl folded (finalize fused).
// Chunk = 4 dt x 1KB; lane = kslotgrp*16 + (d&15). (proven)
// ---------------------------------------------------------------------------
__global__ __launch_bounds__(256) void sdpa_prepV8(const float* __restrict__ V,
                                                   const float* __restrict__ lPart,
                                                   uchar* __restrict__ VT) {
  __shared__ float Vs[32][65];
  __shared__ float rls[32];
  const int c = blockIdx.x & 127;
  const int b = blockIdx.x >> 7;
  const int t = threadIdx.x;
  {
    const int k = t >> 3;
    const int d0 = (t & 7) * 8;
    const float* src = V + ((size_t)(b * S_N + c * 32 + k)) * D_N + d0;
    f32x4 x0 = *(const f32x4*)(src);
    f32x4 x1 = *(const f32x4*)(src + 4);
#pragma unroll
    for (int j = 0; j < 4; ++j) { Vs[k][d0 + j] = x0[j]; Vs[k][d0 + 4 + j] = x1[j]; }
    if (t < 32) {
      float s = 0.f;
      const float* lp = lPart + b * S_N + c * 32 + t;
#pragma unroll
      for (int j = 0; j < 16; ++j) s += lp[(size_t)j * BS_N];
      rls[t] = 1.0f / s;
    }
  }
  __syncthreads();
  const int d = t >> 2;
  const int kg = t & 3;
  half8 hf;
#pragma unroll
  for (int j = 0; j < 8; ++j) {
    const int cc = kg * 8 + j;
    const int k = (((cc >> 2) & 1) << 4) + (((cc >> 3)) << 2) + (cc & 3);
    hf[j] = (_Float16)(Vs[k][d] * rls[k]);
  }
  const int lane = kg * 16 + (d & 15);
  *(half8*)(VT + ((size_t)(b * NCHUNK + c)) * IMG_CH16 + (d >> 4) * 1024 + lane * 16) = hf;
}

// ---------------------------------------------------------------------------
// apply19: grid 256 = b(4, XCD-paired) x qt(64 tiles of 64 q); block 1024 =
// 16 waves = qsub(2, 32 q) x kq(8, 16 chunks). Per kq-group both K and V are
// staged ONCE into dbuf LDS (qsub1: K(it+1), qsub0: V(it+1)); all operands
// fp16. Per iter: stage(it+1) | SB | QK(it) from kslab (8 MFMA) + exp/cvt |
// PV(it) from vslab (8 MFMA) | vmcnt(0) | barrier.
// LDS: 8 kq x 2 par x (K 4KB + V 4KB) = 128KB; merge Comb aliases.
// ---------------------------------------------------------------------------
__global__ __launch_bounds__(1024, 4) void sdpa_apply19(const float* __restrict__ Q,
                                                        const uchar* __restrict__ K16,
                                                        const uchar* __restrict__ VTimg,
                                                        float* __restrict__ Out) {
  __shared__ __attribute__((aligned(16))) uchar sm[131072];  // slabs; Comb aliases

  const int tid = threadIdx.x, lane = tid & 63, w = tid >> 6;
  const int l15 = lane & 15, g4 = lane >> 4;
  const int qsub = w >> 3, kq = w & 7;
  const int xcd = blockIdx.x & 7;
  const int b = xcd >> 1;
  const int qt = ((blockIdx.x >> 3) << 1) | (xcd & 1);  // [0,64), tiles of 64 q

  // Q B-frags (fp16): this wave's 32 q rows (2 qg x 2 d-halves)
  half8 qf[2][2];
#pragma unroll
  for (int qg = 0; qg < 2; ++qg) {
    const int qRow = qt * 64 + qsub * 32 + qg * 16 + l15;
    const float* Qp = Q + ((size_t)(b * S_N + qRow)) * D_N;
    f32x4 x0 = *(const f32x4*)(Qp + g4 * 8);
    f32x4 x1 = *(const f32x4*)(Qp + g4 * 8 + 4);
    f32x4 y0 = *(const f32x4*)(Qp + 32 + g4 * 8);
    f32x4 y1 = *(const f32x4*)(Qp + 36 + g4 * 8);
    x0 *= QSC; x1 *= QSC; y0 *= QSC; y1 *= QSC;
#pragma unroll
    for (int j = 0; j < 4; ++j) {
      qf[qg][0][j] = (_Float16)x0[j]; qf[qg][0][4 + j] = (_Float16)x1[j];
      qf[qg][1][j] = (_Float16)y0[j]; qf[qg][1][4 + j] = (_Float16)y1[j];
    }
  }

  f32x4 accO[2][4];
#pragma unroll
  for (int qg = 0; qg < 2; ++qg)
#pragma unroll
    for (int dt = 0; dt < 4; ++dt) accO[qg][dt] = (f32x4){0.f, 0.f, 0.f, 0.f};

  const uchar* Kc = K16 + ((size_t)(b * NCHUNK + kq * 16)) * IMG_CH16 + lane * 16;
  const uchar* Vc = VTimg + ((size_t)(b * NCHUNK + kq * 16)) * IMG_CH16 + lane * 16;
  uchar* const slab = sm + kq * 16384;    // [par][ K 4KB | V 4KB ]
  const int l16 = lane * 16;

// qsub0 stages V chunk IT, qsub1 stages K chunk IT, into parity PAR
#define STAGE(IT, PAR)                                                         \
  {                                                                            \
    uchar* dst = slab + (PAR) * 8192 + (qsub == 0 ? 4096 : 0);                 \
    const uchar* src = (qsub == 0 ? Vc : Kc) + (size_t)(IT) * IMG_CH16;        \
    _Pragma("unroll")                                                          \
    for (int s = 0; s < 4; ++s) gld16(src + s * 1024, dst + s * 1024);         \
  }

  // prologue: stage K(0),V(0) -> parity 0
  STAGE(0, 0)
  asm volatile("s_waitcnt vmcnt(0)" ::: "memory");
  __syncthreads();

#pragma unroll 1
  for (int it = 0; it < 16; ++it) {
    const int par = it & 1;
    if (it < 15) STAGE(it + 1, par ^ 1)   // flies under QK+PV (~600cy)
    __builtin_amdgcn_sched_barrier(0);    // stage issues before compute

    const uchar* ks = slab + par * 8192;
    const uchar* vs = ks + 4096;

    // QK(it): A = K frags from LDS, B = Q fp16 regs -> P (exp2, fp16)
    half8 paF[2];
#pragma unroll
    for (int kt = 0; kt < 2; ++kt) {
      half8 kf0 = *(const half8*)(ks + kt * 2048 + l16);
      half8 kf1 = *(const half8*)(ks + kt * 2048 + 1024 + l16);
#pragma unroll
      for (int qg = 0; qg < 2; ++qg) {
        f32x4 acc = {0.f, 0.f, 0.f, 0.f};
        acc = MFMAH(kf0, qf[qg][0], acc);
        acc = MFMAH(kf1, qf[qg][1], acc);
#pragma unroll
        for (int rr = 0; rr < 4; ++rr)
          paF[qg][kt * 4 + rr] = (_Float16)exp2f(acc[rr]);
      }
    }

    // PV(it): A = P regs, B = permuted VT frags from LDS
#pragma unroll
    for (int dt = 0; dt < 4; ++dt) {
      half8 vf = *(const half8*)(vs + dt * 1024 + l16);
#pragma unroll
      for (int qg = 0; qg < 2; ++qg)
        accO[qg][dt] = MFMAH(paF[qg], vf, accO[qg][dt]);
    }

    asm volatile("s_waitcnt vmcnt(0)" ::: "memory");  // stage(it+1) landed
    __syncthreads();                                   // visible to the pair
  }

#undef STAGE

  // merge 8 kq partials per qsub, two 16-q phases (Comb aliases the slabs)
  float* Comb = (float*)sm;
#pragma unroll
  for (int qg = 0; qg < 2; ++qg) {
    __syncthreads();   // all waves' slab reads done / previous phase consumed
    {
      float* CombW = Comb + w * (16 * 68);
#pragma unroll
      for (int dt = 0; dt < 4; ++dt)
#pragma unroll
        for (int r = 0; r < 4; ++r)
          CombW[((g4 << 2) + r) * 68 + dt * 16 + l15] = accO[qg][dt][r];
    }
    __syncthreads();
    {
      const int qs2 = tid >> 9;            // 0..1
      const int row = (tid >> 5) & 15;     // 0..15
      const int c2 = (tid & 31) * 2;       // 0..62
      f32x2 s = {0.f, 0.f};
#pragma unroll
      for (int kq2 = 0; kq2 < 8; ++kq2)
        s += *(const f32x2*)(Comb + (qs2 * 8 + kq2) * (16 * 68) + row * 68 + c2);
      *(f32x2*)(Out + ((size_t)(b * S_N + qt * 64 + qs2 * 32 + qg * 16 + row)) * D_N + c2) = s;
    }
  }
}

extern "C" void kernel_launch(void* const* d_in, const int* in_sizes, int n_in,
                              void* d_out, int out_size, void* d_ws, size_t ws_size,
                              hipStream_t stream) {
  (void)in_sizes; (void)n_in; (void)out_size;
  const float* Q = (const float*)d_in[0];
  const float* K = (const float*)d_in[1];
  const float* V = (const float*)d_in[2];
  float* out = (float*)d_out;
  uchar* ws = (uchar*)d_ws;

  const size_t img16 = (size_t)B_N * NCHUNK * IMG_CH16;        // 2 MB
  const size_t offK16 = 0;
  const size_t offQ16 = img16;                                 // VT16 aliases after stats
  const size_t offLP = 2 * img16;
  const size_t need = offLP + (size_t)16 * BS_N * 4;           // 5.05 MB (proven)

  if (ws_size < need) return;
  float* lPart = (float*)(ws + offLP);

  sdpa_prepKQ19<<<dim3(1024), dim3(256), 0, stream>>>(K, Q, ws + offK16, ws + offQ16);
  sdpa_stats16<<<dim3(1024), dim3(256), 0, stream>>>(ws + offK16, ws + offQ16, lPart);
  sdpa_prepV8<<<dim3(512), dim3(256), 0, stream>>>(V, lPart, ws + offQ16);
  sdpa_apply19<<<dim3(256), dim3(1024), 0, stream>>>(Q, ws + offK16, ws + offQ16, out);
}